// Round 1
// baseline (5381.013 us; speedup 1.0000x reference)
//
#include <hip/hip_runtime.h>
#include <hip/hip_bf16.h>
#include <math.h>

typedef short bf16x8 __attribute__((ext_vector_type(8)));
typedef float f32x4 __attribute__((ext_vector_type(4)));
typedef __hip_bfloat16 bf16;

#define NEGV -1e10f
#define LOGEPS -9.210340371976182f  // log(1e-4)
#define HL2PI 0.9189385332046727f   // 0.5*log(2*pi)

__device__ __forceinline__ f32x4 mfma16(bf16x8 a, bf16x8 b, f32x4 c) {
  return __builtin_amdgcn_mfma_f32_16x16x32_bf16(a, b, c, 0, 0, 0);
}
__device__ __forceinline__ bf16x8 ld8(const bf16* p) { return *(const bf16x8*)(const void*)p; }
__device__ __forceinline__ float b2f(bf16 v) { return __bfloat162float(v); }
__device__ __forceinline__ bf16 f2b(float v) { return __float2bfloat16(v); }

// ---------------------------------------------------------------- prep
// Converts weights/activations to bf16 layouts (K-contiguous), builds ar_win
// (padded K=96), bias2 = b_ih+b_hh, pads ow2 to 176 rows, zeros barrier.
__global__ void k_prep(const float* __restrict__ inputs, const float* __restrict__ mels,
                       const float* __restrict__ pw0, const float* __restrict__ pw1,
                       const float* __restrict__ wih, const float* __restrict__ bih,
                       const float* __restrict__ bhh, const float* __restrict__ ow0,
                       const float* __restrict__ ow1, const float* __restrict__ ow2,
                       const float* __restrict__ ob2,
                       bf16* ib, bf16* ar, bf16* w0p, bf16* w1b, bf16* wihb, float* bias2,
                       bf16* ow0Eb, bf16* ow0Mb, bf16* ow1b, bf16* ow2pb, float* ob2p,
                       int* bar) {
  int t0 = blockIdx.x * blockDim.x + threadIdx.x;
  int nt = gridDim.x * blockDim.x;
  if (t0 == 0) { bar[0] = 0; bar[1] = 0; }
  for (int i = t0; i < 8*128*512; i += nt) ib[i] = f2b(inputs[i]);
  for (int i = t0; i < 2048*96; i += nt) {
    int r = i / 96, d = i - r * 96; int t = r >> 3, b = r & 7;
    float v = (d < 80 && t > 0) ? mels[((size_t)b*80 + d)*256 + (t-1)] : 0.f;
    ar[i] = f2b(v);
  }
  for (int i = t0; i < 256*96; i += nt) {
    int j = i / 96, d = i - j * 96;
    w0p[i] = f2b(d < 80 ? pw0[j*80 + d] : 0.f);
  }
  for (int i = t0; i < 256*256; i += nt) w1b[i] = f2b(pw1[i]);
  for (int i = t0; i < 2048*256; i += nt) wihb[i] = f2b(wih[i]);
  for (int i = t0; i < 2048; i += nt) bias2[i] = bih[i] + bhh[i];
  for (int i = t0; i < 256*512; i += nt) {
    int j = i >> 9, k = i & 511;
    ow0Eb[i] = f2b(ow0[(size_t)j*1024 + k]);
    ow0Mb[i] = f2b(ow0[(size_t)j*1024 + 512 + k]);
  }
  for (int i = t0; i < 256*256; i += nt) ow1b[i] = f2b(ow1[i]);
  for (int i = t0; i < 176*256; i += nt) {
    int r = i >> 8;
    ow2pb[i] = f2b(r < 161 ? ow2[i] : 0.f);
  }
  for (int i = t0; i < 176; i += nt) ob2p[i] = (i < 161) ? ob2[i] : 0.f;
}

// ---------------------------------------------------------------- generic MFMA GEMM
// C[r][c] = act(sum_k A[r][k]*W[c][k] + bias[c]); A (MxK) bf16, W (NxK) bf16.
// M,N multiples of 64; K multiple of 32. flags: 1=relu, 2=bf16 out.
// grid = (N/64, M/64), block = 256 (4 waves; wave w -> rows [w*16,w*16+16)).
__global__ __launch_bounds__(256) void k_gemm(const bf16* __restrict__ A, const bf16* __restrict__ W,
                                              const float* __restrict__ bias, void* __restrict__ Cout,
                                              int M, int N, int K, int flags) {
  int wave = threadIdx.x >> 6, lane = threadIdx.x & 63;
  int l16 = lane & 15, quad = lane >> 4;
  int row0 = blockIdx.y * 64 + wave * 16;
  int col0 = blockIdx.x * 64;
  const bf16* arow = A + (size_t)(row0 + l16) * K + quad * 8;
  f32x4 acc[4] = {};
  for (int kt = 0; kt < K; kt += 32) {
    bf16x8 af = ld8(arow + kt);
#pragma unroll
    for (int nt = 0; nt < 4; nt++) {
      bf16x8 wf = ld8(W + (size_t)(col0 + nt*16 + l16) * K + kt + quad * 8);
      acc[nt] = mfma16(af, wf, acc[nt]);
    }
  }
#pragma unroll
  for (int nt = 0; nt < 4; nt++) {
    int col = col0 + nt * 16 + l16;
    float bv = bias ? bias[col] : 0.f;
#pragma unroll
    for (int r = 0; r < 4; r++) {
      int row = row0 + quad * 4 + r;
      float v = acc[nt][r] + bv;
      if (flags & 1) v = v > 0.f ? v : 0.f;
      if (flags & 2) ((bf16*)Cout)[(size_t)row * N + col] = f2b(v);
      else ((float*)Cout)[(size_t)row * N + col] = v;
    }
  }
}

// ---------------------------------------------------------------- LSTM (sequential, 64 blocks)
// Block k owns units [k*8,k*8+8) for all 4 gates x 8 batches (thread = one dot, K=512).
// Hand-rolled device-scope barrier per step (all 64 blocks trivially co-resident).
__global__ __launch_bounds__(256) void k_lstm(const float* __restrict__ gx,
                                              const float* __restrict__ whh,
                                              float* __restrict__ Hf, bf16* __restrict__ Hb,
                                              int* __restrict__ bar) {
  __shared__ float h_lds[8 * 516];  // +4 pad: bank-skew across batches
  __shared__ float g_lds[256];
  int tid = threadIdx.x, blk = blockIdx.x;
  int u = tid >> 5, g = (tid >> 3) & 3, b = tid & 7;
  int j = g * 512 + blk * 8 + u;
  const float* wrow = whh + (size_t)j * 512;
  float c = 0.f;
  for (int t = 0; t < 256; t++) {
    if (t == 0) {
      for (int i = tid; i < 8 * 516; i += 256) h_lds[i] = 0.f;
    } else {
      for (int i = tid; i < 4096; i += 256) {
        int bb = i >> 9, k = i & 511;
        h_lds[bb * 516 + k] = Hf[(size_t)(t - 1) * 4096 + i];
      }
    }
    __syncthreads();
    float acc = gx[((size_t)t * 8 + b) * 2048 + j];
    const float* hb = h_lds + b * 516;
#pragma unroll 8
    for (int k = 0; k < 512; k += 4) {
      float4 wv = *(const float4*)(wrow + k);
      float4 hv = *(const float4*)(hb + k);
      acc += wv.x * hv.x + wv.y * hv.y + wv.z * hv.z + wv.w * hv.w;
    }
    g_lds[g * 64 + u * 8 + b] = acc;
    __syncthreads();
    if (tid < 64) {
      float gi = g_lds[tid], gf = g_lds[64 + tid], gg = g_lds[128 + tid], go = g_lds[192 + tid];
      float si = 1.f / (1.f + expf(-gi));
      float sf = 1.f / (1.f + expf(-gf));
      float so = 1.f / (1.f + expf(-go));
      c = sf * c + si * tanhf(gg);
      float h = so * tanhf(c);
      int cu = tid >> 3, cb = tid & 7;
      size_t hidx = (size_t)t * 4096 + cb * 512 + (blk * 8 + cu);
      Hf[hidx] = h;
      Hb[hidx] = f2b(h);
    }
    // device-scope barrier: release writes, arrive, spin (relaxed), acquire.
    __threadfence();
    __syncthreads();
    if (tid == 0) {
      int arrived = __hip_atomic_fetch_add(bar, 1, __ATOMIC_ACQ_REL, __HIP_MEMORY_SCOPE_AGENT) + 1;
      if (arrived == 64 * (t + 1)) {
        __hip_atomic_store(bar + 1, t + 1, __ATOMIC_RELEASE, __HIP_MEMORY_SCOPE_AGENT);
      } else {
        while (__hip_atomic_load(bar + 1, __ATOMIC_RELAXED, __HIP_MEMORY_SCOPE_AGENT) < t + 1) {}
      }
    }
    __syncthreads();
    __threadfence();
  }
}

// ---------------------------------------------------------------- output net + emission (parallel over t,b)
// One block per (t,b): a0=relu(base+hterm) -> LDS bf16; a1=relu(a0@ow1^T+ob1) via MFMA;
// p=a1@ow2p^T+ob2p via MFMA; Gaussian log-lik + mask -> em, tv.
#define LDA1 264  // 256 + 8 bf16 pad (bank skew for ds_read_b128 column frags)
__global__ __launch_bounds__(256, 2) void k_out(const bf16* __restrict__ base, const float* __restrict__ hterm,
                                                const bf16* __restrict__ w1, const bf16* __restrict__ w2,
                                                const float* __restrict__ ob1, const float* __restrict__ ob2p,
                                                const float* __restrict__ mels, const int* __restrict__ ilen,
                                                float* __restrict__ em, float* __restrict__ tv) {
  __shared__ __align__(16) bf16 a_buf[128 * LDA1];
  __shared__ float ht[256];
  __shared__ float xt[80];
  __shared__ float ob2s[176];
  int tb = blockIdx.x, t = tb >> 3, b = tb & 7;
  int tid = threadIdx.x;
  ht[tid] = hterm[(size_t)tb * 256 + tid];
  if (tid < 80) xt[tid] = mels[((size_t)b * 80 + tid) * 256 + t];
  if (tid < 176) ob2s[tid] = ob2p[tid];
  __syncthreads();
  const bf16* bb = base + (size_t)b * 128 * 256;
  for (int i = 0; i < 128; i++) {
    float v = b2f(bb[i * 256 + tid]) + ht[tid];
    a_buf[i * LDA1 + tid] = f2b(v > 0.f ? v : 0.f);
  }
  __syncthreads();
  int wave = tid >> 6, lane = tid & 63, l16 = lane & 15, quad = lane >> 4;
  // stage B: wave covers cols [wave*64, wave*64+64), all 128 rows
  f32x4 accB[8][4] = {};
  for (int kt = 0; kt < 256; kt += 32) {
    bf16x8 wf[4];
#pragma unroll
    for (int nt = 0; nt < 4; nt++)
      wf[nt] = ld8(w1 + (size_t)(wave * 64 + nt * 16 + l16) * 256 + kt + quad * 8);
#pragma unroll
    for (int mt = 0; mt < 8; mt++) {
      bf16x8 af = ld8(a_buf + (mt * 16 + l16) * LDA1 + kt + quad * 8);
#pragma unroll
      for (int nt = 0; nt < 4; nt++) accB[mt][nt] = mfma16(af, wf[nt], accB[mt][nt]);
    }
  }
  __syncthreads();  // done reading a0
#pragma unroll
  for (int nt = 0; nt < 4; nt++) {
    int col = wave * 64 + nt * 16 + l16;
    float bv = ob1[col];
#pragma unroll
    for (int mt = 0; mt < 8; mt++)
#pragma unroll
      for (int r = 0; r < 4; r++) {
        int row = mt * 16 + quad * 4 + r;
        float v = accB[mt][nt][r] + bv;
        a_buf[row * LDA1 + col] = f2b(v > 0.f ? v : 0.f);
      }
  }
  __syncthreads();
  // stage C: wave covers rows [(wave*2)*16, +32), all 11 col-tiles (176 cols, 161 real)
  f32x4 accC[2][11] = {};
  for (int kt = 0; kt < 256; kt += 32) {
    bf16x8 af0 = ld8(a_buf + ((wave * 2 + 0) * 16 + l16) * LDA1 + kt + quad * 8);
    bf16x8 af1 = ld8(a_buf + ((wave * 2 + 1) * 16 + l16) * LDA1 + kt + quad * 8);
#pragma unroll
    for (int nt = 0; nt < 11; nt++) {
      bf16x8 wf = ld8(w2 + (size_t)(nt * 16 + l16) * 256 + kt + quad * 8);
      accC[0][nt] = mfma16(af0, wf, accC[0][nt]);
      accC[1][nt] = mfma16(af1, wf, accC[1][nt]);
    }
  }
  int my_len = ilen[b];
  float xd[5];
#pragma unroll
  for (int q = 0; q < 5; q++) xd[q] = xt[q * 16 + l16];
#pragma unroll
  for (int m2 = 0; m2 < 2; m2++)
#pragma unroll
    for (int r = 0; r < 4; r++) {
      int row = (wave * 2 + m2) * 16 + quad * 4 + r;
      float pv[11];
#pragma unroll
      for (int nt = 0; nt < 11; nt++) pv[nt] = accC[m2][nt][r] + ob2s[nt * 16 + l16];
      float s = 0.f;
#pragma unroll
      for (int q = 0; q < 5; q++) {
        float mean = pv[q], sh = pv[q + 5];
        float sp = fmaxf(sh, 0.f) + log1pf(expf(-fabsf(sh)));
        float sd = sp + 0.001f;
        float z = (xd[q] - mean) / sd;
        s += -0.5f * z * z - logf(sd);
      }
      s += __shfl_xor(s, 1); s += __shfl_xor(s, 2);
      s += __shfl_xor(s, 4); s += __shfl_xor(s, 8);
      float emv = (row < my_len) ? (s - 80.f * HL2PI) : 0.f;
      if (l16 == 0) {
        em[(size_t)tb * 128 + row] = emv;
        tv[(size_t)tb * 128 + row] = pv[10];
      }
    }
}

// ---------------------------------------------------------------- HMM forward (8 blocks, 1 wave each)
__device__ __forceinline__ float lad(float a, float b) {
  float mx = fmaxf(a, b), mn = fminf(a, b);
  return mx + log1pf(expf(mn - mx));
}
__global__ __launch_bounds__(64) void k_hmm(const float* __restrict__ em, const float* __restrict__ tv,
                                            const int* __restrict__ ilen, const int* __restrict__ mlen,
                                            float* __restrict__ out) {
  int b = blockIdx.x, lane = threadIdx.x;
  int len = ilen[b], ml = mlen[b];
  bool m0 = lane < len, m1 = (64 + lane) < len;
  float la0 = 0.f, la1 = 0.f, lp = 0.f;
  size_t base = (size_t)b * 128 + lane;
  float e0n = em[base], e1n = em[base + 64];
  float v0n = tv[base], v1n = tv[base + 64];
  for (int t = 0; t < 256; t++) {
    float e0 = e0n, e1 = e1n, v0 = v0n, v1 = v1n;
    if (t < 255) {
      size_t idx = base + (size_t)(t + 1) * 1024;
      e0n = em[idx]; e1n = em[idx + 64];
      v0n = tv[idx]; v1n = tv[idx + 64];
    }
    if (t == 0) {
      la0 = (lane == 0 ? 0.f : NEGV) + e0;
      la1 = NEGV + e1;
    } else {
      float L0 = log1pf(expf(-fabsf(v0))), L1 = log1pf(expf(-fabsf(v1)));
      float ls0 = fmaxf(-(fmaxf(v0, 0.f) + L0), LOGEPS);   // log clip(sigmoid(-tv))
      float lm0 = fmaxf(-(fmaxf(-v0, 0.f) + L0), LOGEPS);  // log clip(sigmoid(tv))
      float ls1 = fmaxf(-(fmaxf(v1, 0.f) + L1), LOGEPS);
      float lm1 = fmaxf(-(fmaxf(-v1, 0.f) + L1), LOGEPS);
      float stay0 = la0 + ls0, stay1 = la1 + ls1;
      float mv0 = la0 + lm0, mv1 = la1 + lm1;
      float pm0 = __shfl_up(mv0, 1);
      float pm1 = __shfl_up(mv1, 1);
      float mv0_63 = __shfl(mv0, 63);
      float le0 = (lane == 0) ? NEGV : pm0;
      float le1 = (lane == 0) ? mv0_63 : pm1;
      float o0 = lad(stay0, le0), o1 = lad(stay1, le1);
      o0 = m0 ? o0 : NEGV; o1 = m1 ? o1 : NEGV;
      la0 = e0 + o0; la1 = e1 + o1;
    }
    float mx = fmaxf(la0, la1);
#pragma unroll
    for (int s = 1; s < 64; s <<= 1) mx = fmaxf(mx, __shfl_xor(mx, s));
    float sm = expf(la0 - mx) + expf(la1 - mx);
#pragma unroll
    for (int s = 1; s < 64; s <<= 1) sm += __shfl_xor(sm, s);
    float lc = mx + logf(sm);
    la0 -= lc; la1 -= lc;
    size_t o = 8 + ((size_t)b * 256 + t) * 128 + lane;
    out[o] = la0;
    out[o + 64] = la1;
    if (t < ml) lp += lc;
  }
  if (lane == 0) out[b] = lp;
}

// ---------------------------------------------------------------- launch
extern "C" void kernel_launch(void* const* d_in, const int* in_sizes, int n_in,
                              void* d_out, int out_size, void* d_ws, size_t ws_size,
                              hipStream_t stream) {
  const float* inputs = (const float*)d_in[0];
  const float* mels   = (const float*)d_in[1];
  const float* pw0    = (const float*)d_in[2];
  const float* pw1    = (const float*)d_in[3];
  const float* wih    = (const float*)d_in[4];
  const float* whh    = (const float*)d_in[5];
  const float* bih    = (const float*)d_in[6];
  const float* bhh    = (const float*)d_in[7];
  const float* ow0    = (const float*)d_in[8];
  const float* ob0    = (const float*)d_in[9];
  const float* ow1    = (const float*)d_in[10];
  const float* ob1    = (const float*)d_in[11];
  const float* ow2    = (const float*)d_in[12];
  const float* ob2    = (const float*)d_in[13];
  const int* ilen     = (const int*)d_in[14];
  const int* mlen     = (const int*)d_in[15];
  float* out = (float*)d_out;

  char* w = (char*)d_ws;
  size_t off = 0;
  auto carve = [&](size_t bytes) -> char* {
    char* p = w + off;
    off = (off + bytes + 255) & ~(size_t)255;
    return p;
  };
  bf16*  ib     = (bf16*)carve(8*128*512 * 2);   // inputs bf16
  bf16*  ar     = (bf16*)carve(2048*96 * 2);     // ar_win padded K=96
  bf16*  w0p    = (bf16*)carve(256*96 * 2);
  bf16*  w1b    = (bf16*)carve(256*256 * 2);
  bf16*  wihb   = (bf16*)carve(2048*256 * 2);
  float* bias2  = (float*)carve(2048 * 4);
  bf16*  ow0Eb  = (bf16*)carve(256*512 * 2);
  bf16*  ow0Mb  = (bf16*)carve(256*512 * 2);
  bf16*  ow1b   = (bf16*)carve(256*256 * 2);
  bf16*  ow2pb  = (bf16*)carve(176*256 * 2);
  float* ob2p   = (float*)carve(176 * 4);
  bf16*  pre1   = (bf16*)carve(2048*256 * 2);
  bf16*  pre2   = (bf16*)carve(2048*256 * 2);
  float* gx     = (float*)carve((size_t)2048*2048 * 4);
  bf16*  baseb  = (bf16*)carve(1024*256 * 2);
  float* Hf     = (float*)carve((size_t)256*4096 * 4);
  bf16*  Hb     = (bf16*)carve((size_t)256*4096 * 2);
  float* hterm  = (float*)carve((size_t)2048*256 * 4);
  float* emb    = (float*)carve((size_t)2048*128 * 4);
  float* tvb    = (float*)carve((size_t)2048*128 * 4);
  int*   bar    = (int*)carve(256);

  k_prep<<<512, 256, 0, stream>>>(inputs, mels, pw0, pw1, wih, bih, bhh, ow0, ow1, ow2, ob2,
                                  ib, ar, w0p, w1b, wihb, bias2, ow0Eb, ow0Mb, ow1b, ow2pb, ob2p, bar);
  // prenet L1: (2048x96)@(256x96)^T -> relu bf16
  k_gemm<<<dim3(4, 32), 256, 0, stream>>>(ar, w0p, nullptr, pre1, 2048, 256, 96, 1 | 2);
  // prenet L2: (2048x256)@(256x256)^T -> relu bf16
  k_gemm<<<dim3(4, 32), 256, 0, stream>>>(pre1, w1b, nullptr, pre2, 2048, 256, 256, 1 | 2);
  // gates_x: (2048x256)@(2048x256)^T + (b_ih+b_hh) -> fp32
  k_gemm<<<dim3(32, 32), 256, 0, stream>>>(pre2, wihb, bias2, gx, 2048, 2048, 256, 0);
  // base: inputs@ow0_E^T + ob0 -> bf16 (no relu yet; hterm added later)
  k_gemm<<<dim3(4, 16), 256, 0, stream>>>(ib, ow0Eb, ob0, baseb, 1024, 256, 512, 2);
  // sequential LSTM over 256 steps
  k_lstm<<<64, 256, 0, stream>>>(gx, whh, Hf, Hb, bar);
  // hterm: H@ow0_M^T -> fp32
  k_gemm<<<dim3(4, 32), 256, 0, stream>>>(Hb, ow0Mb, nullptr, hterm, 2048, 256, 512, 0);
  // output net + emission, parallel over (t,b)
  k_out<<<2048, 256, 0, stream>>>(baseb, hterm, ow1b, ow2pb, ob1, ob2p, mels, ilen, emb, tvb);
  // HMM forward + outputs
  k_hmm<<<8, 64, 0, stream>>>(emb, tvb, ilen, mlen, out);
}

// Round 2
// 1616.118 us; speedup vs baseline: 3.3296x; 3.3296x over previous
//
#include <hip/hip_runtime.h>
#include <hip/hip_bf16.h>
#include <math.h>

typedef short bf16x8 __attribute__((ext_vector_type(8)));
typedef float f32x4 __attribute__((ext_vector_type(4)));
typedef __hip_bfloat16 bf16;

#define NEGV -1e10f
#define LOGEPS -9.210340371976182f  // log(1e-4)
#define HL2PI 0.9189385332046727f   // 0.5*log(2*pi)

__device__ __forceinline__ f32x4 mfma16(bf16x8 a, bf16x8 b, f32x4 c) {
  return __builtin_amdgcn_mfma_f32_16x16x32_bf16(a, b, c, 0, 0, 0);
}
__device__ __forceinline__ bf16x8 ld8(const bf16* p) { return *(const bf16x8*)(const void*)p; }
__device__ __forceinline__ float b2f(bf16 v) { return __bfloat162float(v); }
__device__ __forceinline__ bf16 f2b(float v) { return __float2bfloat16(v); }

// ---------------------------------------------------------------- prep
__global__ void k_prep(const float* __restrict__ inputs, const float* __restrict__ mels,
                       const float* __restrict__ pw0, const float* __restrict__ pw1,
                       const float* __restrict__ wih, const float* __restrict__ whh,
                       const float* __restrict__ bih, const float* __restrict__ bhh,
                       const float* __restrict__ ow0, const float* __restrict__ ow1,
                       const float* __restrict__ ow2, const float* __restrict__ ob2,
                       bf16* ib, bf16* ar, bf16* w0p, bf16* w1b, bf16* wihb, bf16* whhb,
                       float* bias2, bf16* ow0Eb, bf16* ow0Mb, bf16* ow1b, bf16* ow2pb,
                       float* ob2p, int* bar) {
  int t0 = blockIdx.x * blockDim.x + threadIdx.x;
  int nt = gridDim.x * blockDim.x;
  if (t0 == 0) { bar[0] = 0; bar[1] = 0; }
  for (int i = t0; i < 8*128*512; i += nt) ib[i] = f2b(inputs[i]);
  for (int i = t0; i < 2048*96; i += nt) {
    int r = i / 96, d = i - r * 96; int t = r >> 3, b = r & 7;
    float v = (d < 80 && t > 0) ? mels[((size_t)b*80 + d)*256 + (t-1)] : 0.f;
    ar[i] = f2b(v);
  }
  for (int i = t0; i < 256*96; i += nt) {
    int j = i / 96, d = i - j * 96;
    w0p[i] = f2b(d < 80 ? pw0[j*80 + d] : 0.f);
  }
  for (int i = t0; i < 256*256; i += nt) w1b[i] = f2b(pw1[i]);
  for (int i = t0; i < 2048*256; i += nt) wihb[i] = f2b(wih[i]);
  for (int i = t0; i < 2048*512; i += nt) whhb[i] = f2b(whh[i]);
  for (int i = t0; i < 2048; i += nt) bias2[i] = bih[i] + bhh[i];
  for (int i = t0; i < 256*512; i += nt) {
    int j = i >> 9, k = i & 511;
    ow0Eb[i] = f2b(ow0[(size_t)j*1024 + k]);
    ow0Mb[i] = f2b(ow0[(size_t)j*1024 + 512 + k]);
  }
  for (int i = t0; i < 256*256; i += nt) ow1b[i] = f2b(ow1[i]);
  for (int i = t0; i < 176*256; i += nt) {
    int r = i >> 8;
    ow2pb[i] = f2b(r < 161 ? ow2[i] : 0.f);
  }
  for (int i = t0; i < 176; i += nt) ob2p[i] = (i < 161) ? ob2[i] : 0.f;
}

// ---------------------------------------------------------------- generic MFMA GEMM
// C[r][c] = act(sum_k A[r][k]*W[c][k] + bias[c]); A (MxK) bf16, W (NxK) bf16.
__global__ __launch_bounds__(256) void k_gemm(const bf16* __restrict__ A, const bf16* __restrict__ W,
                                              const float* __restrict__ bias, void* __restrict__ Cout,
                                              int M, int N, int K, int flags) {
  int wave = threadIdx.x >> 6, lane = threadIdx.x & 63;
  int l16 = lane & 15, quad = lane >> 4;
  int row0 = blockIdx.y * 64 + wave * 16;
  int col0 = blockIdx.x * 64;
  const bf16* arow = A + (size_t)(row0 + l16) * K + quad * 8;
  f32x4 acc[4] = {};
  for (int kt = 0; kt < K; kt += 32) {
    bf16x8 af = ld8(arow + kt);
#pragma unroll
    for (int nt = 0; nt < 4; nt++) {
      bf16x8 wf = ld8(W + (size_t)(col0 + nt*16 + l16) * K + kt + quad * 8);
      acc[nt] = mfma16(af, wf, acc[nt]);
    }
  }
#pragma unroll
  for (int nt = 0; nt < 4; nt++) {
    int col = col0 + nt * 16 + l16;
    float bv = bias ? bias[col] : 0.f;
#pragma unroll
    for (int r = 0; r < 4; r++) {
      int row = row0 + quad * 4 + r;
      float v = acc[nt][r] + bv;
      if (flags & 1) v = v > 0.f ? v : 0.f;
      if (flags & 2) ((bf16*)Cout)[(size_t)row * N + col] = f2b(v);
      else ((float*)Cout)[(size_t)row * N + col] = v;
    }
  }
}

// ---------------------------------------------------------------- LSTM v2
// 16 blocks x 512 threads (8 waves). whh slice lives in VGPRs as MFMA B-frags
// (loaded once). Per step: gather h (MALL, relaxed agent atomics, double-buffered)
// -> LDS -> 16 MFMAs/wave -> epilogue -> h store (relaxed agent atomics) ->
// relaxed counter barrier. NO cache-wide fences in the loop (keeps L2 intact).
__global__ __launch_bounds__(512) void k_lstm(const float* __restrict__ gx,
                                              const bf16* __restrict__ whhb,
                                              bf16* __restrict__ Hb,
                                              unsigned long long* __restrict__ hg,
                                              int* __restrict__ bar) {
  __shared__ __align__(16) bf16 h_lds[16][520];   // [batch(pad16)][unit], +8 pad
  __shared__ float g_lds[4 * 32 * 8];             // [gate][unit][batch]
  __shared__ unsigned short ho_lds[256];          // h out, [unit][batch] bf16 bits
  const int tid = threadIdx.x, q = blockIdx.x;
  const int wave = tid >> 6, lane = tid & 63, l16 = lane & 15, quad = lane >> 4;
  const int g = wave >> 1, un = wave & 1;
  const int j = g * 512 + q * 32 + un * 16 + l16;  // this lane's gate row
  bf16x8 Bf[16];
#pragma unroll
  for (int c = 0; c < 16; c++) Bf[c] = ld8(whhb + (size_t)j * 512 + c * 32 + quad * 8);
  {
    bf16* hp = &h_lds[0][0];
    bf16 z = f2b(0.f);
    for (int i = tid; i < 16 * 520; i += 512) hp[i] = z;  // rows 8..15 stay 0 forever
  }
  float cst = 0.f;
  const int u_own = tid >> 3, b_own = tid & 7;
  for (int t = 0; t < 256; t++) {
    if (t > 0) {
      unsigned long long* src = hg + (size_t)(t & 1) * 1024;
#pragma unroll
      for (int r = 0; r < 2; r++) {
        int idx = tid + 512 * r;            // 0..1023 (uint64 = 4 bf16)
        int b = idx >> 7, u4 = idx & 127;
        unsigned long long v = __hip_atomic_load(src + idx, __ATOMIC_RELAXED, __HIP_MEMORY_SCOPE_AGENT);
        *(unsigned long long*)&h_lds[b][u4 * 4] = v;
      }
    }
    __syncthreads();
    f32x4 acc = {};
#pragma unroll
    for (int c = 0; c < 16; c++) {
      bf16x8 a = ld8(&h_lds[l16][c * 32 + quad * 8]);
      acc = mfma16(a, Bf[c], acc);
    }
    if (quad < 2) {  // C rows 0..7 are the real batches
#pragma unroll
      for (int r = 0; r < 4; r++) {
        int b = quad * 4 + r;
        g_lds[(g * 32 + un * 16 + l16) * 8 + b] = acc[r] + gx[((size_t)t * 8 + b) * 2048 + j];
      }
    }
    __syncthreads();
    if (tid < 256) {
      float gi = g_lds[(0 * 32 + u_own) * 8 + b_own];
      float gf = g_lds[(1 * 32 + u_own) * 8 + b_own];
      float gg = g_lds[(2 * 32 + u_own) * 8 + b_own];
      float go = g_lds[(3 * 32 + u_own) * 8 + b_own];
      float si = 1.f / (1.f + expf(-gi));
      float sf = 1.f / (1.f + expf(-gf));
      float so = 1.f / (1.f + expf(-go));
      cst = sf * cst + si * tanhf(gg);
      float h = so * tanhf(cst);
      bf16 hb = f2b(h);
      unsigned short us; __builtin_memcpy(&us, &hb, 2);
      ho_lds[u_own * 8 + b_own] = us;
    }
    __syncthreads();
    if (tid < 128) {  // pack pairs, publish h + persist Hb
      int p = tid >> 3, b = tid & 7;
      unsigned lo = ho_lds[(2 * p) * 8 + b], hi = ho_lds[(2 * p + 1) * 8 + b];
      unsigned v = lo | (hi << 16);
      unsigned* dst32 = (unsigned*)(hg + (size_t)((t + 1) & 1) * 1024);
      __hip_atomic_store(dst32 + b * 256 + q * 16 + p, v, __ATOMIC_RELAXED, __HIP_MEMORY_SCOPE_AGENT);
      ((unsigned*)Hb)[((size_t)t * 8 + b) * 256 + q * 16 + p] = v;
    }
    __syncthreads();  // per-wave vmcnt(0) drain before barrier => h stores at MALL
    if (tid == 0) {
      int arrived = __hip_atomic_fetch_add(bar, 1, __ATOMIC_RELAXED, __HIP_MEMORY_SCOPE_AGENT) + 1;
      if (arrived == 16 * (t + 1)) {
        __hip_atomic_store(bar + 1, t + 1, __ATOMIC_RELAXED, __HIP_MEMORY_SCOPE_AGENT);
      } else {
        while (__hip_atomic_load(bar + 1, __ATOMIC_RELAXED, __HIP_MEMORY_SCOPE_AGENT) < t + 1)
          __builtin_amdgcn_s_sleep(1);
      }
    }
    __syncthreads();
  }
}

// ---------------------------------------------------------------- output net + emission (parallel over t,b)
#define LDA1 264
__global__ __launch_bounds__(256, 2) void k_out(const bf16* __restrict__ base, const float* __restrict__ hterm,
                                                const bf16* __restrict__ w1, const bf16* __restrict__ w2,
                                                const float* __restrict__ ob1, const float* __restrict__ ob2p,
                                                const float* __restrict__ mels, const int* __restrict__ ilen,
                                                float* __restrict__ em, float* __restrict__ tv) {
  __shared__ __align__(16) bf16 a_buf[128 * LDA1];
  __shared__ float ht[256];
  __shared__ float xt[80];
  __shared__ float ob2s[176];
  int tb = blockIdx.x, t = tb >> 3, b = tb & 7;
  int tid = threadIdx.x;
  ht[tid] = hterm[(size_t)tb * 256 + tid];
  if (tid < 80) xt[tid] = mels[((size_t)b * 80 + tid) * 256 + t];
  if (tid < 176) ob2s[tid] = ob2p[tid];
  __syncthreads();
  const bf16* bb = base + (size_t)b * 128 * 256;
  for (int i = 0; i < 128; i++) {
    float v = b2f(bb[i * 256 + tid]) + ht[tid];
    a_buf[i * LDA1 + tid] = f2b(v > 0.f ? v : 0.f);
  }
  __syncthreads();
  int wave = tid >> 6, lane = tid & 63, l16 = lane & 15, quad = lane >> 4;
  f32x4 accB[8][4] = {};
  for (int kt = 0; kt < 256; kt += 32) {
    bf16x8 wf[4];
#pragma unroll
    for (int nt = 0; nt < 4; nt++)
      wf[nt] = ld8(w1 + (size_t)(wave * 64 + nt * 16 + l16) * 256 + kt + quad * 8);
#pragma unroll
    for (int mt = 0; mt < 8; mt++) {
      bf16x8 af = ld8(a_buf + (mt * 16 + l16) * LDA1 + kt + quad * 8);
#pragma unroll
      for (int nt = 0; nt < 4; nt++) accB[mt][nt] = mfma16(af, wf[nt], accB[mt][nt]);
    }
  }
  __syncthreads();
#pragma unroll
  for (int nt = 0; nt < 4; nt++) {
    int col = wave * 64 + nt * 16 + l16;
    float bv = ob1[col];
#pragma unroll
    for (int mt = 0; mt < 8; mt++)
#pragma unroll
      for (int r = 0; r < 4; r++) {
        int row = mt * 16 + quad * 4 + r;
        float v = accB[mt][nt][r] + bv;
        a_buf[row * LDA1 + col] = f2b(v > 0.f ? v : 0.f);
      }
  }
  __syncthreads();
  f32x4 accC[2][11] = {};
  for (int kt = 0; kt < 256; kt += 32) {
    bf16x8 af0 = ld8(a_buf + ((wave * 2 + 0) * 16 + l16) * LDA1 + kt + quad * 8);
    bf16x8 af1 = ld8(a_buf + ((wave * 2 + 1) * 16 + l16) * LDA1 + kt + quad * 8);
#pragma unroll
    for (int nt = 0; nt < 11; nt++) {
      bf16x8 wf = ld8(w2 + (size_t)(nt * 16 + l16) * 256 + kt + quad * 8);
      accC[0][nt] = mfma16(af0, wf, accC[0][nt]);
      accC[1][nt] = mfma16(af1, wf, accC[1][nt]);
    }
  }
  int my_len = ilen[b];
  float xd[5];
#pragma unroll
  for (int q = 0; q < 5; q++) xd[q] = xt[q * 16 + l16];
#pragma unroll
  for (int m2 = 0; m2 < 2; m2++)
#pragma unroll
    for (int r = 0; r < 4; r++) {
      int row = (wave * 2 + m2) * 16 + quad * 4 + r;
      float pv[11];
#pragma unroll
      for (int nt = 0; nt < 11; nt++) pv[nt] = accC[m2][nt][r] + ob2s[nt * 16 + l16];
      float s = 0.f;
#pragma unroll
      for (int q = 0; q < 5; q++) {
        float mean = pv[q], sh = pv[q + 5];
        float sp = fmaxf(sh, 0.f) + log1pf(expf(-fabsf(sh)));
        float sd = sp + 0.001f;
        float z = (xd[q] - mean) / sd;
        s += -0.5f * z * z - logf(sd);
      }
      s += __shfl_xor(s, 1); s += __shfl_xor(s, 2);
      s += __shfl_xor(s, 4); s += __shfl_xor(s, 8);
      float emv = (row < my_len) ? (s - 80.f * HL2PI) : 0.f;
      if (l16 == 0) {
        em[(size_t)tb * 128 + row] = emv;
        tv[(size_t)tb * 128 + row] = pv[10];
      }
    }
}

// ---------------------------------------------------------------- HMM forward (8 blocks, 1 wave each)
__device__ __forceinline__ float lad(float a, float b) {
  float mx = fmaxf(a, b), mn = fminf(a, b);
  return mx + log1pf(expf(mn - mx));
}
__global__ __launch_bounds__(64) void k_hmm(const float* __restrict__ em, const float* __restrict__ tv,
                                            const int* __restrict__ ilen, const int* __restrict__ mlen,
                                            float* __restrict__ out) {
  int b = blockIdx.x, lane = threadIdx.x;
  int len = ilen[b], ml = mlen[b];
  bool m0 = lane < len, m1 = (64 + lane) < len;
  float la0 = 0.f, la1 = 0.f, lp = 0.f;
  size_t base = (size_t)b * 128 + lane;
  float e0n = em[base], e1n = em[base + 64];
  float v0n = tv[base], v1n = tv[base + 64];
  for (int t = 0; t < 256; t++) {
    float e0 = e0n, e1 = e1n, v0 = v0n, v1 = v1n;
    if (t < 255) {
      size_t idx = base + (size_t)(t + 1) * 1024;
      e0n = em[idx]; e1n = em[idx + 64];
      v0n = tv[idx]; v1n = tv[idx + 64];
    }
    if (t == 0) {
      la0 = (lane == 0 ? 0.f : NEGV) + e0;
      la1 = NEGV + e1;
    } else {
      float L0 = log1pf(expf(-fabsf(v0))), L1 = log1pf(expf(-fabsf(v1)));
      float ls0 = fmaxf(-(fmaxf(v0, 0.f) + L0), LOGEPS);
      float lm0 = fmaxf(-(fmaxf(-v0, 0.f) + L0), LOGEPS);
      float ls1 = fmaxf(-(fmaxf(v1, 0.f) + L1), LOGEPS);
      float lm1 = fmaxf(-(fmaxf(-v1, 0.f) + L1), LOGEPS);
      float stay0 = la0 + ls0, stay1 = la1 + ls1;
      float mv0 = la0 + lm0, mv1 = la1 + lm1;
      float pm0 = __shfl_up(mv0, 1);
      float pm1 = __shfl_up(mv1, 1);
      float mv0_63 = __shfl(mv0, 63);
      float le0 = (lane == 0) ? NEGV : pm0;
      float le1 = (lane == 0) ? mv0_63 : pm1;
      float o0 = lad(stay0, le0), o1 = lad(stay1, le1);
      o0 = m0 ? o0 : NEGV; o1 = m1 ? o1 : NEGV;
      la0 = e0 + o0; la1 = e1 + o1;
    }
    float mx = fmaxf(la0, la1);
#pragma unroll
    for (int s = 1; s < 64; s <<= 1) mx = fmaxf(mx, __shfl_xor(mx, s));
    float sm = expf(la0 - mx) + expf(la1 - mx);
#pragma unroll
    for (int s = 1; s < 64; s <<= 1) sm += __shfl_xor(sm, s);
    float lc = mx + logf(sm);
    la0 -= lc; la1 -= lc;
    size_t o = 8 + ((size_t)b * 256 + t) * 128 + lane;
    out[o] = la0;
    out[o + 64] = la1;
    if (t < ml) lp += lc;
  }
  if (lane == 0) out[b] = lp;
}

// ---------------------------------------------------------------- launch
extern "C" void kernel_launch(void* const* d_in, const int* in_sizes, int n_in,
                              void* d_out, int out_size, void* d_ws, size_t ws_size,
                              hipStream_t stream) {
  const float* inputs = (const float*)d_in[0];
  const float* mels   = (const float*)d_in[1];
  const float* pw0    = (const float*)d_in[2];
  const float* pw1    = (const float*)d_in[3];
  const float* wih    = (const float*)d_in[4];
  const float* whh    = (const float*)d_in[5];
  const float* bih    = (const float*)d_in[6];
  const float* bhh    = (const float*)d_in[7];
  const float* ow0    = (const float*)d_in[8];
  const float* ob0    = (const float*)d_in[9];
  const float* ow1    = (const float*)d_in[10];
  const float* ob1    = (const float*)d_in[11];
  const float* ow2    = (const float*)d_in[12];
  const float* ob2    = (const float*)d_in[13];
  const int* ilen     = (const int*)d_in[14];
  const int* mlen     = (const int*)d_in[15];
  float* out = (float*)d_out;

  char* w = (char*)d_ws;
  size_t off = 0;
  auto carve = [&](size_t bytes) -> char* {
    char* p = w + off;
    off = (off + bytes + 255) & ~(size_t)255;
    return p;
  };
  bf16*  ib     = (bf16*)carve(8*128*512 * 2);
  bf16*  ar     = (bf16*)carve(2048*96 * 2);
  bf16*  w0p    = (bf16*)carve(256*96 * 2);
  bf16*  w1b    = (bf16*)carve(256*256 * 2);
  bf16*  wihb   = (bf16*)carve(2048*256 * 2);
  bf16*  whhb   = (bf16*)carve((size_t)2048*512 * 2);
  float* bias2  = (float*)carve(2048 * 4);
  bf16*  ow0Eb  = (bf16*)carve(256*512 * 2);
  bf16*  ow0Mb  = (bf16*)carve(256*512 * 2);
  bf16*  ow1b   = (bf16*)carve(256*256 * 2);
  bf16*  ow2pb  = (bf16*)carve(176*256 * 2);
  float* ob2p   = (float*)carve(176 * 4);
  bf16*  pre1   = (bf16*)carve(2048*256 * 2);
  bf16*  pre2   = (bf16*)carve(2048*256 * 2);
  float* gx     = (float*)carve((size_t)2048*2048 * 4);
  bf16*  baseb  = (bf16*)carve(1024*256 * 2);
  bf16*  Hb     = (bf16*)carve((size_t)256*4096 * 2);
  unsigned long long* hg = (unsigned long long*)carve(2 * 1024 * 8);
  float* hterm  = (float*)carve((size_t)2048*256 * 4);
  float* emb    = (float*)carve((size_t)2048*128 * 4);
  float* tvb    = (float*)carve((size_t)2048*128 * 4);
  int*   bar    = (int*)carve(256);

  k_prep<<<512, 256, 0, stream>>>(inputs, mels, pw0, pw1, wih, whh, bih, bhh, ow0, ow1, ow2, ob2,
                                  ib, ar, w0p, w1b, wihb, whhb, bias2, ow0Eb, ow0Mb, ow1b, ow2pb,
                                  ob2p, bar);
  k_gemm<<<dim3(4, 32), 256, 0, stream>>>(ar, w0p, nullptr, pre1, 2048, 256, 96, 1 | 2);
  k_gemm<<<dim3(4, 32), 256, 0, stream>>>(pre1, w1b, nullptr, pre2, 2048, 256, 256, 1 | 2);
  k_gemm<<<dim3(32, 32), 256, 0, stream>>>(pre2, wihb, bias2, gx, 2048, 2048, 256, 0);
  k_gemm<<<dim3(4, 16), 256, 0, stream>>>(ib, ow0Eb, ob0, baseb, 1024, 256, 512, 2);
  k_lstm<<<16, 512, 0, stream>>>(gx, whhb, Hb, hg, bar);
  k_gemm<<<dim3(4, 32), 256, 0, stream>>>(Hb, ow0Mb, nullptr, hterm, 2048, 256, 512, 0);
  k_out<<<2048, 256, 0, stream>>>(baseb, hterm, ow1b, ow2pb, ob1, ob2p, mels, ilen, emb, tvb);
  k_hmm<<<8, 64, 0, stream>>>(emb, tvb, ilen, mlen, out);
}

// Round 3
// 1481.599 us; speedup vs baseline: 3.6319x; 1.0908x over previous
//
#include <hip/hip_runtime.h>
#include <hip/hip_bf16.h>
#include <math.h>

typedef short bf16x8 __attribute__((ext_vector_type(8)));
typedef float f32x4 __attribute__((ext_vector_type(4)));
typedef __hip_bfloat16 bf16;

#define NEGV -1e10f
#define LOGEPS -9.210340371976182f  // log(1e-4)
#define HL2PI 0.9189385332046727f   // 0.5*log(2*pi)
#define SENT 0xFFFFFFFFFFFFFFFFULL

__device__ __forceinline__ f32x4 mfma16(bf16x8 a, bf16x8 b, f32x4 c) {
  return __builtin_amdgcn_mfma_f32_16x16x32_bf16(a, b, c, 0, 0, 0);
}
__device__ __forceinline__ bf16x8 ld8(const bf16* p) { return *(const bf16x8*)(const void*)p; }
__device__ __forceinline__ float b2f(bf16 v) { return __bfloat162float(v); }
__device__ __forceinline__ bf16 f2b(float v) { return __float2bfloat16(v); }
__device__ __forceinline__ float sh2f(short s) {
  unsigned u = ((unsigned)(unsigned short)s) << 16; float f; __builtin_memcpy(&f, &u, 4); return f;
}
__device__ __forceinline__ short f2sh(float v) {
  bf16 b = f2b(v); short s; __builtin_memcpy(&s, &b, 2); return s;
}

// ---------------------------------------------------------------- prep
__global__ void k_prep(const float* __restrict__ inputs, const float* __restrict__ mels,
                       const float* __restrict__ pw0, const float* __restrict__ pw1,
                       const float* __restrict__ wih, const float* __restrict__ whh,
                       const float* __restrict__ bih, const float* __restrict__ bhh,
                       const float* __restrict__ ow0, const float* __restrict__ ow1,
                       const float* __restrict__ ow2, const float* __restrict__ ob2,
                       bf16* ib, bf16* ar, bf16* w0p, bf16* w1b, bf16* wihb, bf16* whhb,
                       float* bias2, bf16* ow0Eb, bf16* ow0Mb, bf16* ow1b, bf16* ow2pb,
                       float* ob2p, unsigned long long* hg) {
  int t0 = blockIdx.x * blockDim.x + threadIdx.x;
  int nt = gridDim.x * blockDim.x;
  for (int i = t0; i < 256 * 1024; i += nt) hg[i] = SENT;  // sentinel for data-poll sync
  for (int i = t0; i < 8*128*512; i += nt) ib[i] = f2b(inputs[i]);
  for (int i = t0; i < 2048*96; i += nt) {
    int r = i / 96, d = i - r * 96; int t = r >> 3, b = r & 7;
    float v = (d < 80 && t > 0) ? mels[((size_t)b*80 + d)*256 + (t-1)] : 0.f;
    ar[i] = f2b(v);
  }
  for (int i = t0; i < 256*96; i += nt) {
    int j = i / 96, d = i - j * 96;
    w0p[i] = f2b(d < 80 ? pw0[j*80 + d] : 0.f);
  }
  for (int i = t0; i < 256*256; i += nt) w1b[i] = f2b(pw1[i]);
  for (int i = t0; i < 2048*256; i += nt) wihb[i] = f2b(wih[i]);
  for (int i = t0; i < 2048*512; i += nt) whhb[i] = f2b(whh[i]);
  for (int i = t0; i < 2048; i += nt) bias2[i] = bih[i] + bhh[i];
  for (int i = t0; i < 256*512; i += nt) {
    int j = i >> 9, k = i & 511;
    ow0Eb[i] = f2b(ow0[(size_t)j*1024 + k]);
    ow0Mb[i] = f2b(ow0[(size_t)j*1024 + 512 + k]);
  }
  for (int i = t0; i < 256*256; i += nt) ow1b[i] = f2b(ow1[i]);
  for (int i = t0; i < 176*256; i += nt) {
    int r = i >> 8;
    ow2pb[i] = f2b(r < 161 ? ow2[i] : 0.f);
  }
  for (int i = t0; i < 176; i += nt) ob2p[i] = (i < 161) ? ob2[i] : 0.f;
}

// ---------------------------------------------------------------- generic MFMA GEMM
__global__ __launch_bounds__(256) void k_gemm(const bf16* __restrict__ A, const bf16* __restrict__ W,
                                              const float* __restrict__ bias, void* __restrict__ Cout,
                                              int M, int N, int K, int flags) {
  int wave = threadIdx.x >> 6, lane = threadIdx.x & 63;
  int l16 = lane & 15, quad = lane >> 4;
  int row0 = blockIdx.y * 64 + wave * 16;
  int col0 = blockIdx.x * 64;
  const bf16* arow = A + (size_t)(row0 + l16) * K + quad * 8;
  f32x4 acc[4] = {};
  for (int kt = 0; kt < K; kt += 32) {
    bf16x8 af = ld8(arow + kt);
#pragma unroll
    for (int nt = 0; nt < 4; nt++) {
      bf16x8 wf = ld8(W + (size_t)(col0 + nt*16 + l16) * K + kt + quad * 8);
      acc[nt] = mfma16(af, wf, acc[nt]);
    }
  }
#pragma unroll
  for (int nt = 0; nt < 4; nt++) {
    int col = col0 + nt * 16 + l16;
    float bv = bias ? bias[col] : 0.f;
#pragma unroll
    for (int r = 0; r < 4; r++) {
      int row = row0 + quad * 4 + r;
      float v = acc[nt][r] + bv;
      if (flags & 1) v = v > 0.f ? v : 0.f;
      if (flags & 2) ((bf16*)Cout)[(size_t)row * N + col] = f2b(v);
      else ((float*)Cout)[(size_t)row * N + col] = v;
    }
  }
}

// ---------------------------------------------------------------- LSTM v3: data-is-the-barrier
// 16 blocks x 512 threads. W rows remapped so wave-row m = unit*4+gate: after MFMA
// (A=W static in VGPRs, B=h), lane (quad,l16) holds all 4 gates of unit (wbase+quad),
// batch l16 -> fully in-register epilogue, no LDS staging, 1 syncthreads/step.
// h published per-step to fresh sentinel-initialized buffers via relaxed agent (MALL)
// 8B atomics; consumers poll the data words directly. No flags, no barrier.
__global__ __launch_bounds__(512, 2) void k_lstm(const float* __restrict__ gx,
                                                 const bf16* __restrict__ whhb,
                                                 unsigned long long* __restrict__ hg) {
  __shared__ __align__(16) bf16 h_lds[2][16][520];
  const int tid = threadIdx.x, q = blockIdx.x;
  const int wave = tid >> 6, lane = tid & 63, l16 = lane & 15, quad = lane >> 4;
  // wave-row m = l16 -> gate = m&3, unit_idx = m>>2; global gate row:
  const int jrow = (l16 & 3) * 512 + q * 32 + wave * 4 + (l16 >> 2);
  bf16x8 Af[16];
#pragma unroll
  for (int c = 0; c < 16; c++) Af[c] = ld8(whhb + (size_t)jrow * 512 + c * 32 + quad * 8);
  {
    bf16 z = f2b(0.f);
    bf16* hp = &h_lds[0][0][0];
    for (int i = tid; i < 2 * 16 * 520; i += 512) hp[i] = z;
  }
  __syncthreads();
  const int b_ep = l16 & 7;                       // epilogue batch (l16>=8 lanes: shadow)
  const int gx_col = q * 32 + wave * 4 + quad;    // unit column in gx
  const int w0i = tid, w1i = tid + 512;           // this thread's poll words
  const int b0 = w0i >> 7, u40 = w0i & 127, b1 = w1i >> 7, u41 = w1i & 127;
  const int hword = b_ep * 128 + q * 8 + wave;    // publish word index
  float cst = 0.f;
  for (int t = 0; t < 256; t++) {
    // prefetch gx for this step (overlaps the poll wait below)
    const float* gp = gx + ((size_t)t * 8 + b_ep) * 2048 + gx_col;
    float gx0 = gp[0], gx1 = gp[512], gx2 = gp[1024], gx3 = gp[1536];
    int buf = t & 1;
    if (t > 0) {
      unsigned long long* src = hg + (size_t)(t - 1) * 1024;
      unsigned long long v0, v1;
      do { v0 = __hip_atomic_load(src + w0i, __ATOMIC_RELAXED, __HIP_MEMORY_SCOPE_AGENT); } while (v0 == SENT);
      *(unsigned long long*)&h_lds[buf][b0][u40 * 4] = v0;
      do { v1 = __hip_atomic_load(src + w1i, __ATOMIC_RELAXED, __HIP_MEMORY_SCOPE_AGENT); } while (v1 == SENT);
      *(unsigned long long*)&h_lds[buf][b1][u41 * 4] = v1;
    }
    __syncthreads();  // h_lds[buf] complete; double-buffer removes read/write race
    f32x4 acc = {};
#pragma unroll
    for (int c = 0; c < 16; c++) {
      bf16x8 hf = ld8(&h_lds[buf][l16][c * 32 + quad * 8]);
      acc = mfma16(Af[c], hf, acc);
    }
    // in-register LSTM epilogue: acc[0..3] = i,f,g,o gates of (unit=gx_col, batch=b_ep)
    float gi = acc[0] + gx0, gf = acc[1] + gx1, gg = acc[2] + gx2, go = acc[3] + gx3;
    float si = 1.f / (1.f + expf(-gi));
    float sf = 1.f / (1.f + expf(-gf));
    float so = 1.f / (1.f + expf(-go));
    cst = sf * cst + si * tanhf(gg);
    float h = so * tanhf(cst);
    // gather the 4 quads' h (4 consecutive units) into one 8B word, publish
    unsigned hu = (unsigned short)f2sh(h);
    unsigned h1 = __shfl_xor((int)hu, 16);
    unsigned h2 = __shfl_xor((int)hu, 32);
    unsigned h3 = __shfl_xor((int)h1, 32);
    if (quad == 0 && l16 < 8) {
      unsigned long long w64 = (unsigned long long)hu | ((unsigned long long)h1 << 16) |
                               ((unsigned long long)h2 << 32) | ((unsigned long long)h3 << 48);
      __hip_atomic_store(hg + (size_t)t * 1024 + hword, w64, __ATOMIC_RELAXED, __HIP_MEMORY_SCOPE_AGENT);
    }
  }
}

// ---------------------------------------------------------------- output net + emission (parallel over t,b)
#define LDA1 264
__global__ __launch_bounds__(256, 2) void k_out(const bf16* __restrict__ base, const float* __restrict__ hterm,
                                                const bf16* __restrict__ w1, const bf16* __restrict__ w2,
                                                const float* __restrict__ ob1, const float* __restrict__ ob2p,
                                                const float* __restrict__ mels, const int* __restrict__ ilen,
                                                float* __restrict__ em, float* __restrict__ tv) {
  __shared__ __align__(16) bf16 a_buf[128 * LDA1];
  __shared__ float ht[256];
  __shared__ float xt[80];
  __shared__ float ob2s[176];
  int tb = blockIdx.x, t = tb >> 3, b = tb & 7;
  int tid = threadIdx.x;
  ht[tid] = hterm[(size_t)tb * 256 + tid];
  if (tid < 80) xt[tid] = mels[((size_t)b * 80 + tid) * 256 + t];
  if (tid < 176) ob2s[tid] = ob2p[tid];
  __syncthreads();
  const bf16* bb = base + (size_t)b * 128 * 256;
  {
    int r0 = tid >> 5, c0 = (tid & 31) * 8;
    float hv[8];
#pragma unroll
    for (int j = 0; j < 8; j++) hv[j] = ht[c0 + j];
    for (int i = r0; i < 128; i += 8) {
      bf16x8 bv = ld8(bb + i * 256 + c0);
      bf16x8 ov;
#pragma unroll
      for (int j = 0; j < 8; j++) {
        float v = sh2f(bv[j]) + hv[j];
        ov[j] = f2sh(v > 0.f ? v : 0.f);
      }
      *(bf16x8*)&a_buf[i * LDA1 + c0] = ov;
    }
  }
  __syncthreads();
  int wave = tid >> 6, lane = tid & 63, l16 = lane & 15, quad = lane >> 4;
  f32x4 accB[8][4] = {};
  for (int kt = 0; kt < 256; kt += 32) {
    bf16x8 wf[4];
#pragma unroll
    for (int nt = 0; nt < 4; nt++)
      wf[nt] = ld8(w1 + (size_t)(wave * 64 + nt * 16 + l16) * 256 + kt + quad * 8);
#pragma unroll
    for (int mt = 0; mt < 8; mt++) {
      bf16x8 af = ld8(a_buf + (mt * 16 + l16) * LDA1 + kt + quad * 8);
#pragma unroll
      for (int nt = 0; nt < 4; nt++) accB[mt][nt] = mfma16(af, wf[nt], accB[mt][nt]);
    }
  }
  __syncthreads();
#pragma unroll
  for (int nt = 0; nt < 4; nt++) {
    int col = wave * 64 + nt * 16 + l16;
    float bv = ob1[col];
#pragma unroll
    for (int mt = 0; mt < 8; mt++)
#pragma unroll
      for (int r = 0; r < 4; r++) {
        int row = mt * 16 + quad * 4 + r;
        float v = accB[mt][nt][r] + bv;
        a_buf[row * LDA1 + col] = f2b(v > 0.f ? v : 0.f);
      }
  }
  __syncthreads();
  f32x4 accC[2][11] = {};
  for (int kt = 0; kt < 256; kt += 32) {
    bf16x8 af0 = ld8(a_buf + ((wave * 2 + 0) * 16 + l16) * LDA1 + kt + quad * 8);
    bf16x8 af1 = ld8(a_buf + ((wave * 2 + 1) * 16 + l16) * LDA1 + kt + quad * 8);
#pragma unroll
    for (int nt = 0; nt < 11; nt++) {
      bf16x8 wf = ld8(w2 + (size_t)(nt * 16 + l16) * 256 + kt + quad * 8);
      accC[0][nt] = mfma16(af0, wf, accC[0][nt]);
      accC[1][nt] = mfma16(af1, wf, accC[1][nt]);
    }
  }
  int my_len = ilen[b];
  float xd[5];
#pragma unroll
  for (int q = 0; q < 5; q++) xd[q] = xt[q * 16 + l16];
#pragma unroll
  for (int m2 = 0; m2 < 2; m2++)
#pragma unroll
    for (int r = 0; r < 4; r++) {
      int row = (wave * 2 + m2) * 16 + quad * 4 + r;
      float pv[11];
#pragma unroll
      for (int nt = 0; nt < 11; nt++) pv[nt] = accC[m2][nt][r] + ob2s[nt * 16 + l16];
      float s = 0.f;
#pragma unroll
      for (int q = 0; q < 5; q++) {
        float mean = pv[q], sh = pv[q + 5];
        float sp = fmaxf(sh, 0.f) + log1pf(expf(-fabsf(sh)));
        float sd = sp + 0.001f;
        float z = (xd[q] - mean) / sd;
        s += -0.5f * z * z - logf(sd);
      }
      s += __shfl_xor(s, 1); s += __shfl_xor(s, 2);
      s += __shfl_xor(s, 4); s += __shfl_xor(s, 8);
      float emv = (row < my_len) ? (s - 80.f * HL2PI) : 0.f;
      if (l16 == 0) {
        em[(size_t)tb * 128 + row] = emv;
        tv[(size_t)tb * 128 + row] = pv[10];
      }
    }
}

// ---------------------------------------------------------------- HMM forward (8 blocks, 1 wave each)
__device__ __forceinline__ float lad(float a, float b) {
  float mx = fmaxf(a, b), mn = fminf(a, b);
  return mx + log1pf(expf(mn - mx));
}
__global__ __launch_bounds__(64) void k_hmm(const float* __restrict__ em, const float* __restrict__ tv,
                                            const int* __restrict__ ilen, const int* __restrict__ mlen,
                                            float* __restrict__ out) {
  int b = blockIdx.x, lane = threadIdx.x;
  int len = ilen[b], ml = mlen[b];
  bool m0 = lane < len, m1 = (64 + lane) < len;
  float la0 = 0.f, la1 = 0.f, lp = 0.f;
  size_t base = (size_t)b * 128 + lane;
  float e0n = em[base], e1n = em[base + 64];
  float v0n = tv[base], v1n = tv[base + 64];
  for (int t = 0; t < 256; t++) {
    float e0 = e0n, e1 = e1n, v0 = v0n, v1 = v1n;
    if (t < 255) {
      size_t idx = base + (size_t)(t + 1) * 1024;
      e0n = em[idx]; e1n = em[idx + 64];
      v0n = tv[idx]; v1n = tv[idx + 64];
    }
    if (t == 0) {
      la0 = (lane == 0 ? 0.f : NEGV) + e0;
      la1 = NEGV + e1;
    } else {
      float L0 = log1pf(expf(-fabsf(v0))), L1 = log1pf(expf(-fabsf(v1)));
      float ls0 = fmaxf(-(fmaxf(v0, 0.f) + L0), LOGEPS);
      float lm0 = fmaxf(-(fmaxf(-v0, 0.f) + L0), LOGEPS);
      float ls1 = fmaxf(-(fmaxf(v1, 0.f) + L1), LOGEPS);
      float lm1 = fmaxf(-(fmaxf(-v1, 0.f) + L1), LOGEPS);
      float stay0 = la0 + ls0, stay1 = la1 + ls1;
      float mv0 = la0 + lm0, mv1 = la1 + lm1;
      float pm0 = __shfl_up(mv0, 1);
      float pm1 = __shfl_up(mv1, 1);
      float mv0_63 = __shfl(mv0, 63);
      float le0 = (lane == 0) ? NEGV : pm0;
      float le1 = (lane == 0) ? mv0_63 : pm1;
      float o0 = lad(stay0, le0), o1 = lad(stay1, le1);
      o0 = m0 ? o0 : NEGV; o1 = m1 ? o1 : NEGV;
      la0 = e0 + o0; la1 = e1 + o1;
    }
    float mx = fmaxf(la0, la1);
#pragma unroll
    for (int s = 1; s < 64; s <<= 1) mx = fmaxf(mx, __shfl_xor(mx, s));
    float sm = expf(la0 - mx) + expf(la1 - mx);
#pragma unroll
    for (int s = 1; s < 64; s <<= 1) sm += __shfl_xor(sm, s);
    float lc = mx + logf(sm);
    la0 -= lc; la1 -= lc;
    size_t o = 8 + ((size_t)b * 256 + t) * 128 + lane;
    out[o] = la0;
    out[o + 64] = la1;
    if (t < ml) lp += lc;
  }
  if (lane == 0) out[b] = lp;
}

// ---------------------------------------------------------------- launch
extern "C" void kernel_launch(void* const* d_in, const int* in_sizes, int n_in,
                              void* d_out, int out_size, void* d_ws, size_t ws_size,
                              hipStream_t stream) {
  const float* inputs = (const float*)d_in[0];
  const float* mels   = (const float*)d_in[1];
  const float* pw0    = (const float*)d_in[2];
  const float* pw1    = (const float*)d_in[3];
  const float* wih    = (const float*)d_in[4];
  const float* whh    = (const float*)d_in[5];
  const float* bih    = (const float*)d_in[6];
  const float* bhh    = (const float*)d_in[7];
  const float* ow0    = (const float*)d_in[8];
  const float* ob0    = (const float*)d_in[9];
  const float* ow1    = (const float*)d_in[10];
  const float* ob1    = (const float*)d_in[11];
  const float* ow2    = (const float*)d_in[12];
  const float* ob2    = (const float*)d_in[13];
  const int* ilen     = (const int*)d_in[14];
  const int* mlen     = (const int*)d_in[15];
  float* out = (float*)d_out;

  char* w = (char*)d_ws;
  size_t off = 0;
  auto carve = [&](size_t bytes) -> char* {
    char* p = w + off;
    off = (off + bytes + 255) & ~(size_t)255;
    return p;
  };
  bf16*  ib     = (bf16*)carve(8*128*512 * 2);
  bf16*  ar     = (bf16*)carve(2048*96 * 2);
  bf16*  w0p    = (bf16*)carve(256*96 * 2);
  bf16*  w1b    = (bf16*)carve(256*256 * 2);
  bf16*  wihb   = (bf16*)carve(2048*256 * 2);
  bf16*  whhb   = (bf16*)carve((size_t)2048*512 * 2);
  float* bias2  = (float*)carve(2048 * 4);
  bf16*  ow0Eb  = (bf16*)carve(256*512 * 2);
  bf16*  ow0Mb  = (bf16*)carve(256*512 * 2);
  bf16*  ow1b   = (bf16*)carve(256*256 * 2);
  bf16*  ow2pb  = (bf16*)carve(176*256 * 2);
  float* ob2p   = (float*)carve(176 * 4);
  bf16*  pre1   = (bf16*)carve(2048*256 * 2);
  bf16*  pre2   = (bf16*)carve(2048*256 * 2);
  float* gx     = (float*)carve((size_t)2048*2048 * 4);
  bf16*  baseb  = (bf16*)carve(1024*256 * 2);
  unsigned long long* hg = (unsigned long long*)carve((size_t)256 * 1024 * 8);  // = Hb layout [t*8+b][512] bf16
  float* hterm  = (float*)carve((size_t)2048*256 * 4);
  float* emb    = (float*)carve((size_t)2048*128 * 4);
  float* tvb    = (float*)carve((size_t)2048*128 * 4);

  k_prep<<<512, 256, 0, stream>>>(inputs, mels, pw0, pw1, wih, whh, bih, bhh, ow0, ow1, ow2, ob2,
                                  ib, ar, w0p, w1b, wihb, whhb, bias2, ow0Eb, ow0Mb, ow1b, ow2pb,
                                  ob2p, hg);
  k_gemm<<<dim3(4, 32), 256, 0, stream>>>(ar, w0p, nullptr, pre1, 2048, 256, 96, 1 | 2);
  k_gemm<<<dim3(4, 32), 256, 0, stream>>>(pre1, w1b, nullptr, pre2, 2048, 256, 256, 1 | 2);
  k_gemm<<<dim3(32, 32), 256, 0, stream>>>(pre2, wihb, bias2, gx, 2048, 2048, 256, 0);
  k_gemm<<<dim3(4, 16), 256, 0, stream>>>(ib, ow0Eb, ob0, baseb, 1024, 256, 512, 2);
  k_lstm<<<16, 512, 0, stream>>>(gx, whhb, hg);
  k_gemm<<<dim3(4, 32), 256, 0, stream>>>((const bf16*)hg, ow0Mb, nullptr, hterm, 2048, 256, 512, 0);
  k_out<<<2048, 256, 0, stream>>>(baseb, hterm, ow1b, ow2pb, ob1, ob2p, mels, ilen, emb, tvb);
  k_hmm<<<8, 64, 0, stream>>>(emb, tvb, ilen, mlen, out);
}

// Round 4
// 927.078 us; speedup vs baseline: 5.8043x; 1.5981x over previous
//
#include <hip/hip_runtime.h>
#include <hip/hip_bf16.h>
#include <math.h>

typedef short bf16x8 __attribute__((ext_vector_type(8)));
typedef float f32x4 __attribute__((ext_vector_type(4)));
typedef __hip_bfloat16 bf16;

#define NEGV -1e10f
#define LOGEPS -9.210340371976182f  // log(1e-4)
#define HL2PI 0.9189385332046727f   // 0.5*log(2*pi)
#define SENT 0xFFFFFFFFFFFFFFFFULL

__device__ __forceinline__ f32x4 mfma16(bf16x8 a, bf16x8 b, f32x4 c) {
  return __builtin_amdgcn_mfma_f32_16x16x32_bf16(a, b, c, 0, 0, 0);
}
__device__ __forceinline__ bf16x8 ld8(const bf16* p) { return *(const bf16x8*)(const void*)p; }
__device__ __forceinline__ float b2f(bf16 v) { return __bfloat162float(v); }
__device__ __forceinline__ bf16 f2b(float v) { return __float2bfloat16(v); }
__device__ __forceinline__ float sh2f(short s) {
  unsigned u = ((unsigned)(unsigned short)s) << 16; float f; __builtin_memcpy(&f, &u, 4); return f;
}
__device__ __forceinline__ short f2sh(float v) {
  bf16 b = f2b(v); short s; __builtin_memcpy(&s, &b, 2); return s;
}
// fast transcendentals (v_exp_f32/v_log_f32 based)
__device__ __forceinline__ float fsigm(float x) { return 1.f / (1.f + __expf(-x)); }
__device__ __forceinline__ float ftanh(float x) { return 1.f - 2.f / (1.f + __expf(2.f * x)); }

// ---------------------------------------------------------------- prep
__global__ void k_prep(const float* __restrict__ inputs, const float* __restrict__ mels,
                       const float* __restrict__ pw0, const float* __restrict__ pw1,
                       const float* __restrict__ wih, const float* __restrict__ whh,
                       const float* __restrict__ bih, const float* __restrict__ bhh,
                       const float* __restrict__ ow0, const float* __restrict__ ow1,
                       const float* __restrict__ ow2, const float* __restrict__ ob2,
                       bf16* ib, bf16* ar, bf16* w0p, bf16* w1b, bf16* wihb, bf16* whhb,
                       float* bias2, bf16* ow0Eb, bf16* ow0Mb, bf16* ow1b, bf16* ow2pb,
                       float* ob2p, unsigned long long* hg) {
  int t0 = blockIdx.x * blockDim.x + threadIdx.x;
  int nt = gridDim.x * blockDim.x;
  for (int i = t0; i < 256 * 1024; i += nt) hg[i] = SENT;  // sentinel for data-poll sync
  for (int i = t0; i < 8*128*512; i += nt) ib[i] = f2b(inputs[i]);
  for (int i = t0; i < 2048*96; i += nt) {
    int r = i / 96, d = i - r * 96; int t = r >> 3, b = r & 7;
    float v = (d < 80 && t > 0) ? mels[((size_t)b*80 + d)*256 + (t-1)] : 0.f;
    ar[i] = f2b(v);
  }
  for (int i = t0; i < 256*96; i += nt) {
    int j = i / 96, d = i - j * 96;
    w0p[i] = f2b(d < 80 ? pw0[j*80 + d] : 0.f);
  }
  for (int i = t0; i < 256*256; i += nt) w1b[i] = f2b(pw1[i]);
  for (int i = t0; i < 2048*256; i += nt) wihb[i] = f2b(wih[i]);
  for (int i = t0; i < 2048*512; i += nt) whhb[i] = f2b(whh[i]);
  for (int i = t0; i < 2048; i += nt) bias2[i] = bih[i] + bhh[i];
  for (int i = t0; i < 256*512; i += nt) {
    int j = i >> 9, k = i & 511;
    ow0Eb[i] = f2b(ow0[(size_t)j*1024 + k]);
    ow0Mb[i] = f2b(ow0[(size_t)j*1024 + 512 + k]);
  }
  for (int i = t0; i < 256*256; i += nt) ow1b[i] = f2b(ow1[i]);
  for (int i = t0; i < 176*256; i += nt) {
    int r = i >> 8;
    ow2pb[i] = f2b(r < 161 ? ow2[i] : 0.f);
  }
  for (int i = t0; i < 176; i += nt) ob2p[i] = (i < 161) ? ob2[i] : 0.f;
}

// ---------------------------------------------------------------- generic MFMA GEMM
__global__ __launch_bounds__(256) void k_gemm(const bf16* __restrict__ A, const bf16* __restrict__ W,
                                              const float* __restrict__ bias, void* __restrict__ Cout,
                                              int M, int N, int K, int flags) {
  int wave = threadIdx.x >> 6, lane = threadIdx.x & 63;
  int l16 = lane & 15, quad = lane >> 4;
  int row0 = blockIdx.y * 64 + wave * 16;
  int col0 = blockIdx.x * 64;
  const bf16* arow = A + (size_t)(row0 + l16) * K + quad * 8;
  f32x4 acc[4] = {};
  for (int kt = 0; kt < K; kt += 32) {
    bf16x8 af = ld8(arow + kt);
#pragma unroll
    for (int nt = 0; nt < 4; nt++) {
      bf16x8 wf = ld8(W + (size_t)(col0 + nt*16 + l16) * K + kt + quad * 8);
      acc[nt] = mfma16(af, wf, acc[nt]);
    }
  }
#pragma unroll
  for (int nt = 0; nt < 4; nt++) {
    int col = col0 + nt * 16 + l16;
    float bv = bias ? bias[col] : 0.f;
#pragma unroll
    for (int r = 0; r < 4; r++) {
      int row = row0 + quad * 4 + r;
      float v = acc[nt][r] + bv;
      if (flags & 1) v = v > 0.f ? v : 0.f;
      if (flags & 2) ((bf16*)Cout)[(size_t)row * N + col] = f2b(v);
      else ((float*)Cout)[(size_t)row * N + col] = v;
    }
  }
}

// ---------------------------------------------------------------- LSTM v4
// 16 blocks x 512 threads, data-is-the-barrier (sentinel poll on MALL).
// Changes vs v3: parallel polls; gx software-pipelined (loaded after polls for t+1);
// fragment-order LDS layout [k/8][batch][8] (2-way bank alias = free); 4 independent
// MFMA accumulator chains; fast exp-based sigmoid/tanh; launch_bounds(512,1).
__global__ __launch_bounds__(512, 1) void k_lstm(const float* __restrict__ gx,
                                                 const bf16* __restrict__ whhb,
                                                 unsigned long long* __restrict__ hg) {
  // fragment-order: hb[buf][(c4*16 + batch)*8 + j], c4 = k>>3  (16 KB per buf)
  __shared__ __align__(16) bf16 hb[2][64 * 16 * 8];
  const int tid = threadIdx.x, q = blockIdx.x;
  const int wave = tid >> 6, lane = tid & 63, l16 = lane & 15, quad = lane >> 4;
  const int jrow = (l16 & 3) * 512 + q * 32 + wave * 4 + (l16 >> 2);
  bf16x8 Af[16];
#pragma unroll
  for (int c = 0; c < 16; c++) Af[c] = ld8(whhb + (size_t)jrow * 512 + c * 32 + quad * 8);
  {
    bf16 z = f2b(0.f);
    bf16* hp = &hb[0][0];
    for (int i = tid; i < 2 * 64 * 16 * 8; i += 512) hp[i] = z;
  }
  const int b_ep = l16 & 7;
  const int gx_col = q * 32 + wave * 4 + quad;
  const int w0i = tid, w1i = tid + 512;  // poll words (coalesced per wave)
  // LDS bf16 offset for word w (b = w>>7, u4 = w&127): ((u4>>1)*16 + b)*8 + (u4&1)*4
  const int o0 = (((w0i & 127) >> 1) * 16 + (w0i >> 7)) * 8 + ((w0i & 1) << 2);
  const int o1 = (((w1i & 127) >> 1) * 16 + (w1i >> 7)) * 8 + ((w1i & 1) << 2);
  const int hword = b_ep * 128 + q * 8 + wave;
  float cst = 0.f;
  // preload gx for t=0
  const float* gp0 = gx + (size_t)b_ep * 2048 + gx_col;
  float gx0 = gp0[0], gx1 = gp0[512], gx2 = gp0[1024], gx3 = gp0[1536];
  for (int t = 0; t < 256; t++) {
    int buf = t & 1;
    if (t > 0) {
      const unsigned long long* src = hg + (size_t)(t - 1) * 1024;
      unsigned long long v0 = __hip_atomic_load(src + w0i, __ATOMIC_RELAXED, __HIP_MEMORY_SCOPE_AGENT);
      unsigned long long v1 = __hip_atomic_load(src + w1i, __ATOMIC_RELAXED, __HIP_MEMORY_SCOPE_AGENT);
      while (v0 == SENT || v1 == SENT) {
        if (v0 == SENT) v0 = __hip_atomic_load(src + w0i, __ATOMIC_RELAXED, __HIP_MEMORY_SCOPE_AGENT);
        if (v1 == SENT) v1 = __hip_atomic_load(src + w1i, __ATOMIC_RELAXED, __HIP_MEMORY_SCOPE_AGENT);
      }
      *(unsigned long long*)&hb[buf][o0] = v0;
      *(unsigned long long*)&hb[buf][o1] = v1;
    }
    __syncthreads();
    // prefetch next step's gx (latency hides under MFMA + epilogue + publish)
    int tn = (t + 1) & 255;
    const float* gpn = gx + ((size_t)tn * 8 + b_ep) * 2048 + gx_col;
    float ngx0 = gpn[0], ngx1 = gpn[512], ngx2 = gpn[1024], ngx3 = gpn[1536];
    // 4 independent MFMA chains (4-deep each)
    f32x4 a0 = {}, a1 = {}, a2 = {}, a3 = {};
#pragma unroll
    for (int c = 0; c < 16; c += 4) {
      a0 = mfma16(Af[c + 0], ld8(&hb[buf][(((c + 0) * 4 + quad) * 16 + l16) * 8]), a0);
      a1 = mfma16(Af[c + 1], ld8(&hb[buf][(((c + 1) * 4 + quad) * 16 + l16) * 8]), a1);
      a2 = mfma16(Af[c + 2], ld8(&hb[buf][(((c + 2) * 4 + quad) * 16 + l16) * 8]), a2);
      a3 = mfma16(Af[c + 3], ld8(&hb[buf][(((c + 3) * 4 + quad) * 16 + l16) * 8]), a3);
    }
    f32x4 acc = (a0 + a1) + (a2 + a3);
    // in-register epilogue: acc[0..3] = i,f,g,o of (unit gx_col, batch b_ep)
    float gi = acc[0] + gx0, gf = acc[1] + gx1, gg = acc[2] + gx2, go = acc[3] + gx3;
    cst = fsigm(gf) * cst + fsigm(gi) * ftanh(gg);
    float h = fsigm(go) * ftanh(cst);
    // gather quads 0..3 (4 consecutive units) into one 8B word, publish
    unsigned hu = (unsigned short)f2sh(h);
    unsigned h1 = __shfl_xor((int)hu, 16);
    unsigned h2 = __shfl_xor((int)hu, 32);
    unsigned h3 = __shfl_xor((int)h1, 32);
    if (quad == 0 && l16 < 8) {
      unsigned long long w64 = (unsigned long long)hu | ((unsigned long long)h1 << 16) |
                               ((unsigned long long)h2 << 32) | ((unsigned long long)h3 << 48);
      __hip_atomic_store(hg + (size_t)t * 1024 + hword, w64, __ATOMIC_RELAXED, __HIP_MEMORY_SCOPE_AGENT);
    }
    gx0 = ngx0; gx1 = ngx1; gx2 = ngx2; gx3 = ngx3;
  }
}

// ---------------------------------------------------------------- output net + emission (parallel over t,b)
#define LDA1 264
__global__ __launch_bounds__(256, 2) void k_out(const bf16* __restrict__ base, const float* __restrict__ hterm,
                                                const bf16* __restrict__ w1, const bf16* __restrict__ w2,
                                                const float* __restrict__ ob1, const float* __restrict__ ob2p,
                                                const float* __restrict__ mels, const int* __restrict__ ilen,
                                                float* __restrict__ em, float* __restrict__ tv) {
  __shared__ __align__(16) bf16 a_buf[128 * LDA1];
  __shared__ float ht[256];
  __shared__ float xt[80];
  __shared__ float ob2s[176];
  int tb = blockIdx.x, t = tb >> 3, b = tb & 7;
  int tid = threadIdx.x;
  ht[tid] = hterm[(size_t)tb * 256 + tid];
  if (tid < 80) xt[tid] = mels[((size_t)b * 80 + tid) * 256 + t];
  if (tid < 176) ob2s[tid] = ob2p[tid];
  __syncthreads();
  const bf16* bb = base + (size_t)b * 128 * 256;
  {
    int r0 = tid >> 5, c0 = (tid & 31) * 8;
    float hv[8];
#pragma unroll
    for (int j = 0; j < 8; j++) hv[j] = ht[c0 + j];
    for (int i = r0; i < 128; i += 8) {
      bf16x8 bv = ld8(bb + i * 256 + c0);
      bf16x8 ov;
#pragma unroll
      for (int j = 0; j < 8; j++) {
        float v = sh2f(bv[j]) + hv[j];
        ov[j] = f2sh(v > 0.f ? v : 0.f);
      }
      *(bf16x8*)&a_buf[i * LDA1 + c0] = ov;
    }
  }
  __syncthreads();
  int wave = tid >> 6, lane = tid & 63, l16 = lane & 15, quad = lane >> 4;
  f32x4 accB[8][4] = {};
  for (int kt = 0; kt < 256; kt += 32) {
    bf16x8 wf[4];
#pragma unroll
    for (int nt = 0; nt < 4; nt++)
      wf[nt] = ld8(w1 + (size_t)(wave * 64 + nt * 16 + l16) * 256 + kt + quad * 8);
#pragma unroll
    for (int mt = 0; mt < 8; mt++) {
      bf16x8 af = ld8(a_buf + (mt * 16 + l16) * LDA1 + kt + quad * 8);
#pragma unroll
      for (int nt = 0; nt < 4; nt++) accB[mt][nt] = mfma16(af, wf[nt], accB[mt][nt]);
    }
  }
  __syncthreads();
#pragma unroll
  for (int nt = 0; nt < 4; nt++) {
    int col = wave * 64 + nt * 16 + l16;
    float bv = ob1[col];
#pragma unroll
    for (int mt = 0; mt < 8; mt++)
#pragma unroll
      for (int r = 0; r < 4; r++) {
        int row = mt * 16 + quad * 4 + r;
        float v = accB[mt][nt][r] + bv;
        a_buf[row * LDA1 + col] = f2b(v > 0.f ? v : 0.f);
      }
  }
  __syncthreads();
  f32x4 accC[2][11] = {};
  for (int kt = 0; kt < 256; kt += 32) {
    bf16x8 af0 = ld8(a_buf + ((wave * 2 + 0) * 16 + l16) * LDA1 + kt + quad * 8);
    bf16x8 af1 = ld8(a_buf + ((wave * 2 + 1) * 16 + l16) * LDA1 + kt + quad * 8);
#pragma unroll
    for (int nt = 0; nt < 11; nt++) {
      bf16x8 wf = ld8(w2 + (size_t)(nt * 16 + l16) * 256 + kt + quad * 8);
      accC[0][nt] = mfma16(af0, wf, accC[0][nt]);
      accC[1][nt] = mfma16(af1, wf, accC[1][nt]);
    }
  }
  int my_len = ilen[b];
  float xd[5];
#pragma unroll
  for (int q = 0; q < 5; q++) xd[q] = xt[q * 16 + l16];
#pragma unroll
  for (int m2 = 0; m2 < 2; m2++)
#pragma unroll
    for (int r = 0; r < 4; r++) {
      int row = (wave * 2 + m2) * 16 + quad * 4 + r;
      float pv[11];
#pragma unroll
      for (int nt = 0; nt < 11; nt++) pv[nt] = accC[m2][nt][r] + ob2s[nt * 16 + l16];
      float s = 0.f;
#pragma unroll
      for (int q = 0; q < 5; q++) {
        float mean = pv[q], sh = pv[q + 5];
        float sp = fmaxf(sh, 0.f) + __logf(1.f + __expf(-fabsf(sh)));
        float sd = sp + 0.001f;
        float z = (xd[q] - mean) / sd;
        s += -0.5f * z * z - __logf(sd);
      }
      s += __shfl_xor(s, 1); s += __shfl_xor(s, 2);
      s += __shfl_xor(s, 4); s += __shfl_xor(s, 8);
      float emv = (row < my_len) ? (s - 80.f * HL2PI) : 0.f;
      if (l16 == 0) {
        em[(size_t)tb * 128 + row] = emv;
        tv[(size_t)tb * 128 + row] = pv[10];
      }
    }
}

// ---------------------------------------------------------------- HMM forward (8 blocks, 1 wave each)
__device__ __forceinline__ float lad(float a, float b) {
  float mx = fmaxf(a, b), mn = fminf(a, b);
  return mx + __logf(1.f + __expf(mn - mx));
}
__global__ __launch_bounds__(64) void k_hmm(const float* __restrict__ em, const float* __restrict__ tv,
                                            const int* __restrict__ ilen, const int* __restrict__ mlen,
                                            float* __restrict__ out) {
  int b = blockIdx.x, lane = threadIdx.x;
  int len = ilen[b], ml = mlen[b];
  bool m0 = lane < len, m1 = (64 + lane) < len;
  float la0 = 0.f, la1 = 0.f, lp = 0.f;
  size_t base = (size_t)b * 128 + lane;
  float e0n = em[base], e1n = em[base + 64];
  float v0n = tv[base], v1n = tv[base + 64];
  for (int t = 0; t < 256; t++) {
    float e0 = e0n, e1 = e1n, v0 = v0n, v1 = v1n;
    if (t < 255) {
      size_t idx = base + (size_t)(t + 1) * 1024;
      e0n = em[idx]; e1n = em[idx + 64];
      v0n = tv[idx]; v1n = tv[idx + 64];
    }
    if (t == 0) {
      la0 = (lane == 0 ? 0.f : NEGV) + e0;
      la1 = NEGV + e1;
    } else {
      float L0 = __logf(1.f + __expf(-fabsf(v0))), L1 = __logf(1.f + __expf(-fabsf(v1)));
      float ls0 = fmaxf(-(fmaxf(v0, 0.f) + L0), LOGEPS);
      float lm0 = fmaxf(-(fmaxf(-v0, 0.f) + L0), LOGEPS);
      float ls1 = fmaxf(-(fmaxf(v1, 0.f) + L1), LOGEPS);
      float lm1 = fmaxf(-(fmaxf(-v1, 0.f) + L1), LOGEPS);
      float stay0 = la0 + ls0, stay1 = la1 + ls1;
      float mv0 = la0 + lm0, mv1 = la1 + lm1;
      float pm0 = __shfl_up(mv0, 1);
      float pm1 = __shfl_up(mv1, 1);
      float mv0_63 = __shfl(mv0, 63);
      float le0 = (lane == 0) ? NEGV : pm0;
      float le1 = (lane == 0) ? mv0_63 : pm1;
      float o0 = lad(stay0, le0), o1 = lad(stay1, le1);
      o0 = m0 ? o0 : NEGV; o1 = m1 ? o1 : NEGV;
      la0 = e0 + o0; la1 = e1 + o1;
    }
    float mx = fmaxf(la0, la1);
#pragma unroll
    for (int s = 1; s < 64; s <<= 1) mx = fmaxf(mx, __shfl_xor(mx, s));
    float sm = __expf(la0 - mx) + __expf(la1 - mx);
#pragma unroll
    for (int s = 1; s < 64; s <<= 1) sm += __shfl_xor(sm, s);
    float lc = mx + __logf(sm);
    la0 -= lc; la1 -= lc;
    size_t o = 8 + ((size_t)b * 256 + t) * 128 + lane;
    out[o] = la0;
    out[o + 64] = la1;
    if (t < ml) lp += lc;
  }
  if (lane == 0) out[b] = lp;
}

// ---------------------------------------------------------------- launch
extern "C" void kernel_launch(void* const* d_in, const int* in_sizes, int n_in,
                              void* d_out, int out_size, void* d_ws, size_t ws_size,
                              hipStream_t stream) {
  const float* inputs = (const float*)d_in[0];
  const float* mels   = (const float*)d_in[1];
  const float* pw0    = (const float*)d_in[2];
  const float* pw1    = (const float*)d_in[3];
  const float* wih    = (const float*)d_in[4];
  const float* whh    = (const float*)d_in[5];
  const float* bih    = (const float*)d_in[6];
  const float* bhh    = (const float*)d_in[7];
  const float* ow0    = (const float*)d_in[8];
  const float* ob0    = (const float*)d_in[9];
  const float* ow1    = (const float*)d_in[10];
  const float* ob1    = (const float*)d_in[11];
  const float* ow2    = (const float*)d_in[12];
  const float* ob2    = (const float*)d_in[13];
  const int* ilen     = (const int*)d_in[14];
  const int* mlen     = (const int*)d_in[15];
  float* out = (float*)d_out;

  char* w = (char*)d_ws;
  size_t off = 0;
  auto carve = [&](size_t bytes) -> char* {
    char* p = w + off;
    off = (off + bytes + 255) & ~(size_t)255;
    return p;
  };
  bf16*  ib     = (bf16*)carve(8*128*512 * 2);
  bf16*  ar     = (bf16*)carve(2048*96 * 2);
  bf16*  w0p    = (bf16*)carve(256*96 * 2);
  bf16*  w1b    = (bf16*)carve(256*256 * 2);
  bf16*  wihb   = (bf16*)carve(2048*256 * 2);
  bf16*  whhb   = (bf16*)carve((size_t)2048*512 * 2);
  float* bias2  = (float*)carve(2048 * 4);
  bf16*  ow0Eb  = (bf16*)carve(256*512 * 2);
  bf16*  ow0Mb  = (bf16*)carve(256*512 * 2);
  bf16*  ow1b   = (bf16*)carve(256*256 * 2);
  bf16*  ow2pb  = (bf16*)carve(176*256 * 2);
  float* ob2p   = (float*)carve(176 * 4);
  bf16*  pre1   = (bf16*)carve(2048*256 * 2);
  bf16*  pre2   = (bf16*)carve(2048*256 * 2);
  float* gx     = (float*)carve((size_t)2048*2048 * 4);
  bf16*  baseb  = (bf16*)carve(1024*256 * 2);
  unsigned long long* hg = (unsigned long long*)carve((size_t)256 * 1024 * 8);  // Hb layout [t*8+b][512] bf16
  float* hterm  = (float*)carve((size_t)2048*256 * 4);
  float* emb    = (float*)carve((size_t)2048*128 * 4);
  float* tvb    = (float*)carve((size_t)2048*128 * 4);

  k_prep<<<512, 256, 0, stream>>>(inputs, mels, pw0, pw1, wih, whh, bih, bhh, ow0, ow1, ow2, ob2,
                                  ib, ar, w0p, w1b, wihb, whhb, bias2, ow0Eb, ow0Mb, ow1b, ow2pb,
                                  ob2p, hg);
  k_gemm<<<dim3(4, 32), 256, 0, stream>>>(ar, w0p, nullptr, pre1, 2048, 256, 96, 1 | 2);
  k_gemm<<<dim3(4, 32), 256, 0, stream>>>(pre1, w1b, nullptr, pre2, 2048, 256, 256, 1 | 2);
  k_gemm<<<dim3(32, 32), 256, 0, stream>>>(pre2, wihb, bias2, gx, 2048, 2048, 256, 0);
  k_gemm<<<dim3(4, 16), 256, 0, stream>>>(ib, ow0Eb, ob0, baseb, 1024, 256, 512, 2);
  k_lstm<<<16, 512, 0, stream>>>(gx, whhb, hg);
  k_gemm<<<dim3(4, 32), 256, 0, stream>>>((const bf16*)hg, ow0Mb, nullptr, hterm, 2048, 256, 512, 0);
  k_out<<<2048, 256, 0, stream>>>(baseb, hterm, ow1b, ow2pb, ob1, ob2p, mels, ilen, emb, tvb);
  k_hmm<<<8, 64, 0, stream>>>(emb, tvb, ilen, mlen, out);
}